// Round 3
// baseline (14319.456 us; speedup 1.0000x reference)
//
#include <hip/hip_runtime.h>
#include <hip/hip_cooperative_groups.h>
#include <stdint.h>
#include <math.h>

namespace cg = cooperative_groups;

#define NS 8192
#define NSTEPS 200
#define DBc 128

typedef unsigned int u32;
typedef unsigned short u16;

// ws float-offset layout
#define WS_C1   0          // 8192
#define WS_C2   8192       // 8192
#define WS_PM1  16384      // 128
#define WS_PM2  16512
#define WS_PS1  16640
#define WS_PS2  16768
#define WS_PW1  16896
#define WS_PW2  17024
#define WS_LL   17152      // 2*8192 (parity)
#define WS_IDX  33536      // int[200]
#define WS_ANC_F 33792     // u16[199*8192] => 815104 floats
#define WS_TRACE 848896    // float[200*8192*8]

// ======================= threefry2x32-20 =======================
__device__ __forceinline__ u32 rotl32(u32 v, int r){ return (v<<r)|(v>>(32-r)); }

__device__ __forceinline__ void tf2x32(u32 k0,u32 k1,u32 c0,u32 c1,u32&o0,u32&o1){
  u32 ks2 = k0^k1^0x1BD11BDAu;
  u32 x0=c0+k0, x1=c1+k1;
#define TFR(R) { x0+=x1; x1=rotl32(x1,(R)); x1^=x0; }
  TFR(13) TFR(15) TFR(26) TFR(6)
  x0+=k1;  x1+=ks2+1u;
  TFR(17) TFR(29) TFR(16) TFR(24)
  x0+=ks2; x1+=k0+2u;
  TFR(13) TFR(15) TFR(26) TFR(6)
  x0+=k0;  x1+=k1+3u;
  TFR(17) TFR(29) TFR(16) TFR(24)
  x0+=k1;  x1+=ks2+4u;
  TFR(13) TFR(15) TFR(26) TFR(6)
  x0+=ks2; x1+=k0+5u;
#undef TFR
  o0=x0; o1=x1;
}

// partitionable threefry bits (validated rounds 1-2)
__device__ __forceinline__ u32 jax_bits_elem(u32 k0,u32 k1,u32 i){
  u32 a,b; tf2x32(k0,k1,0u,i,a,b); return a^b;
}

__device__ __forceinline__ void jax_split2(u32 k0,u32 k1,u32&c00,u32&c01,u32&c10,u32&c11){
  tf2x32(k0,k1,0u,0u,c00,c01);
  tf2x32(k0,k1,0u,1u,c10,c11);
}

__device__ __forceinline__ float bits_to_f01(u32 bits){
  return __uint_as_float((bits>>9)|0x3f800000u) - 1.0f;
}

__device__ __forceinline__ float log1pf_acc(float a){
#pragma clang fp contract(off)
  float u = 1.0f + a;
  if (u == 1.0f) return a;
  float l = logf(u);
  return l * (a / (u - 1.0f));
}

__device__ __forceinline__ float erfinv_xla(float x){
#pragma clang fp contract(off)
  float a = -(x*x);
  float w = -log1pf_acc(a);
  float p;
  if (w < 5.0f){
    w = w - 2.5f;
    p = 2.81022636e-08f;
    p = 3.43273939e-07f + p*w;
    p = -3.5233877e-06f + p*w;
    p = -4.39150654e-06f + p*w;
    p = 0.00021858087f  + p*w;
    p = -0.00125372503f + p*w;
    p = -0.00417768164f + p*w;
    p = 0.246640727f    + p*w;
    p = 1.50140941f     + p*w;
  } else {
    w = sqrtf(w) - 3.0f;
    p = -0.000200214257f;
    p = 0.000100950558f + p*w;
    p = 0.00134934322f  + p*w;
    p = -0.00367342844f + p*w;
    p = 0.00573950773f  + p*w;
    p = -0.0076224613f  + p*w;
    p = 0.00943887047f  + p*w;
    p = 1.00167406f     + p*w;
    p = 2.83297682f     + p*w;
  }
  return p*x;
}

__device__ __forceinline__ float jax_normal_elem(u32 k0,u32 k1,u32 i){
#pragma clang fp contract(off)
  float f = bits_to_f01(jax_bits_elem(k0,k1,i));
  float u = f*2.0f + (-0.99999994039535522f);
  u = fmaxf(-0.99999994039535522f, u);
  return 1.41421356237309515f * erfinv_xla(u);
}

__device__ __forceinline__ float jax_uniform01_scalar(u32 k0,u32 k1){
  return bits_to_f01(jax_bits_elem(k0,k1,0u));
}

// ======================= wave helpers =======================
__device__ __forceinline__ float wave_max(float v){
  #pragma unroll
  for(int m=1;m<64;m<<=1) v=fmaxf(v,__shfl_xor(v,m,64));
  return v;
}
__device__ __forceinline__ float wave_sum(float v){
  #pragma unroll
  for(int m=1;m<64;m<<=1) v+=__shfl_xor(v,m,64);
  return v;
}
__device__ __forceinline__ float wave_incl_scan(float v,int lane){
  #pragma unroll
  for(int o=1;o<64;o<<=1){ float u=__shfl_up(v,o,64); if(lane>=o) v+=u; }
  return v;
}
__device__ __forceinline__ float all_max128(const float* p,int lane){
  return wave_max(fmaxf(p[lane],p[lane+64]));
}
__device__ __forceinline__ float all_sum128(const float* p,int lane){
  return wave_sum(p[lane]+p[lane+64]);
}
// exclusive prefix of 128-array at position idx (idx wave-uniform)
__device__ __forceinline__ float excl_prefix128_at(const float* p,int lane,int idx){
  float a=p[lane], b=p[lane+64];
  float totA=wave_sum(a);
  float sa=__shfl_up(a,1,64); if(lane==0) sa=0.0f;
  float ea=wave_incl_scan(sa,lane);
  float sb=__shfl_up(b,1,64); if(lane==0) sb=0.0f;
  float eb=wave_incl_scan(sb,lane);
  float hi=totA+eb;
  return (idx<64)? __shfl(ea,idx,64) : __shfl(hi,idx-64,64);
}

__device__ __forceinline__ int bsearch8192(const float* c,float v){
  int lo=0,hi=NS;
  while(lo<hi){ int mid=(lo+hi)>>1; if(c[mid]<v) lo=mid+1; else hi=mid; }
  return lo>NS-1?NS-1:lo;
}

// packed lower-tri Cholesky, same op order as round-2 k_pre
__device__ void chol8(const float* A,float* L){
  for(int c=0;c<8;c++){
    for(int r=c;r<8;r++){
      float s=A[r*8+c];
      for(int k=0;k<c;k++) s-=L[r*(r+1)/2+k]*L[c*(c+1)/2+k];
      L[r*(r+1)/2+c]=(r==c)? sqrtf(s) : s/L[c*(c+1)/2+c];
    }
  }
}

// ======================= fused cooperative kernel =======================
__global__ __launch_bounds__(128) void k_all(
    const float* __restrict__ obs, const float* __restrict__ inp,
    const float* __restrict__ mean, const float* __restrict__ icov,
    const float* __restrict__ coeff, const float* __restrict__ ecov,
    const float* __restrict__ refst, const float* __restrict__ Om,
    const float* __restrict__ ph, const float* __restrict__ Cm,
    const int* __restrict__ seedp, float* wsf, float* __restrict__ out)
{
  cg::grid_group grid = cg::this_grid();
  const int tid=threadIdx.x;
  const int lane=tid&63;
  const int wid=blockIdx.x*2+(tid>>6);
  const int i=blockIdx.x*128+tid;

  float* C1=wsf+WS_C1;  float* C2=wsf+WS_C2;
  float* PM1=wsf+WS_PM1; float* PM2=wsf+WS_PM2;
  float* PS1=wsf+WS_PS1; float* PS2=wsf+WS_PS2;
  float* PW1=wsf+WS_PW1; float* PW2=wsf+WS_PW2;
  float* LLb=wsf+WS_LL;
  int* IDX=(int*)(wsf+WS_IDX);
  u16* ANC=(u16*)(wsf+WS_ANC_F);
  float* TR=wsf+WS_TRACE;

  // --- init: redundant per-thread (registers) ---
  float LEp[36];
  { float L0p[36];
    chol8(icov,L0p); chol8(ecov,LEp);
    const float SSQc=(float)(0.1*0.1); (void)SSQc;
    // state0
    u32 kq0,kq1,ki0,ki1;
    { int seed=seedp[0]; u32 a0,a1,b0,b1;
      jax_split2(0u,(u32)seed,a0,a1,b0,b1);
      kq0=a0; kq1=a1; ki0=b0; ki1=b1; }
    float st[8];
    if(i==NS-1){ for(int d=0;d<8;d++) st[d]=refst[d]; }
    else {
      float eps[8];
      for(int d=0;d<8;d++) eps[d]=jax_normal_elem(ki0,ki1,(u32)(i*8+d));
      for(int d=0;d<8;d++){ float m=0.0f; for(int k=0;k<=d;k++) m+=eps[k]*L0p[d*(d+1)/2+k]; st[d]=mean[d]+m; }
    }
    for(int d=0;d<8;d++) TR[i*8+d]=st[d];

    float c_ll=4.0f*logf((float)(2.0*M_PI*0.1*0.1));
    float hc1=0.0f; for(int d=0;d<8;d++) hc1+=logf(LEp[d*(d+1)/2+d]);
    float hc2=4.0f*logf((float)(2.0*M_PI));
    const float SSQ=(float)(0.1*0.1);
    float lw=0.0f;
    u32 key0=kq0, key1=kq1;

    // ================= main scan =================
    for(int t=1;t<NSTEPS;t++){
      // key chain (redundant, identical across threads)
      u32 ka0,ka1,kr0,kr1,kst0,kst1;
      { u32 n0,n1,s0,s1; jax_split2(key0,key1,n0,n1,s0,s1); key0=n0; key1=n1;
        u32 t0,t1; jax_split2(s0,s1,t0,t1,ka0,ka1);
        u32 u0,u1; jax_split2(t0,t1,u0,u1,kr0,kr1);
        u32 d0,d1; jax_split2(u0,u1,d0,d1,kst0,kst1); }

      // --- phase A (state-exact arithmetic, same as round-2 k_a) ---
      float z[12];
      for(int d=0;d<8;d++) z[d]=st[d];
      for(int k=0;k<4;k++) z[8+k]=inp[t*4+k];
      float ax[8]={0,0,0,0,0,0,0,0};
      for(int j=0;j<DBc;j++){
        float dot=0.0f;
        #pragma unroll
        for(int k=0;k<12;k++) dot+=z[k]*Om[j*12+k];
        float b=cosf(dot+ph[j]);
        #pragma unroll
        for(int d=0;d<8;d++) ax[d]+=b*coeff[d*DBc+j];
      }
      float S=0.0f;
      for(int d=0;d<8;d++){
        float m=0.0f;
        #pragma unroll
        for(int k=0;k<8;k++) m+=ax[k]*Cm[d*8+k];
        float r=obs[t*8+d]-m; S+=r*r;
      }
      float ll=(-0.5f*S)/SSQ - c_ll;
      float sol[8]; float q=0.0f;
      for(int d=0;d<8;d++){
        float s=refst[t*8+d]-ax[d];
        for(int k=0;k<d;k++) s-=LEp[d*(d+1)/2+k]*sol[k];
        sol[d]=s/LEp[d*(d+1)/2+d];
        q+=sol[d]*sol[d];
      }
      float h=(-0.5f*q - hc1) - hc2;
      float s1v=ll+lw, s2v=s1v+h;
      LLb[(t&1)*NS + i]=ll;
      float wm1=wave_max(s1v), wm2=wave_max(s2v);
      if(lane==0){ PM1[wid]=wm1; PM2[wid]=wm2; }
      grid.sync();

      // --- B1: global max, exp, partial sums ---
      float M1=all_max128(PM1,lane), M2=all_max128(PM2,lane);
      float e1=expf(s1v-M1), e2=expf(s2v-M2);
      float q1=wave_sum(e1), q2=wave_sum(e2);
      if(lane==0){ PS1[wid]=q1; PS2[wid]=q2; }
      grid.sync();

      // --- B2: totals, normalize, wave scans ---
      float T1=all_sum128(PS1,lane), T2=all_sum128(PS2,lane);
      float w1=e1/T1, w2=e2/T2;
      float in1=wave_incl_scan(w1,lane), in2=wave_incl_scan(w2,lane);
      if(lane==63){ PW1[wid]=in1; PW2[wid]=in2; }
      grid.sync();

      // --- B3: global cumsum ---
      float off1=excl_prefix128_at(PW1,lane,wid);
      float off2=excl_prefix128_at(PW2,lane,wid);
      C1[i]=off1+in1;
      C2[i]=off2+in2;
      grid.sync();

      // --- C: resample index, propagate, reweight ---
      int aidx;
      if(i==NS-1){
        float u2=jax_uniform01_scalar(kr0,kr1);
        aidx=bsearch8192(C2,u2);
      } else {
        float u1=jax_uniform01_scalar(ka0,ka1);
        float pos=((float)i+u1)*(1.0f/8192.0f);
        aidx=bsearch8192(C1,pos);
      }
      ANC[(size_t)(t-1)*NS+i]=(u16)aidx;

      if(i==NS-1){ for(int d=0;d<8;d++) st[d]=refst[t*8+d]; }
      else {
        float eps[8];
        for(int d=0;d<8;d++) eps[d]=jax_normal_elem(kst0,kst1,(u32)(i*8+d));
        for(int d=0;d<8;d++){ float m=0.0f; for(int k=0;k<=d;k++) m+=eps[k]*LEp[d*(d+1)/2+k]; st[d]=ax[d]+m; }
      }
      float S2n=0.0f;
      for(int d=0;d<8;d++){
        float m=0.0f;
        #pragma unroll
        for(int k=0;k<8;k++) m+=st[k]*Cm[d*8+k];
        float r=obs[t*8+d]-m; S2n+=r*r;
      }
      float lln=(-0.5f*S2n)/SSQ - c_ll;
      lw=lln-LLb[(t&1)*NS + aidx];
      float* TRt=TR+(size_t)t*NS*8;
      for(int d=0;d<8;d++) TRt[i*8+d]=st[d];
      // no sync needed here: LL parity-buffered; C1/C2 next written after 3 syncs
    }

    // ================= final selection =================
    float wm=wave_max(lw);
    if(lane==0) PM1[wid]=wm;
    grid.sync();
    float M=all_max128(PM1,lane);
    float e=expf(lw-M);
    float qs=wave_sum(e);
    if(lane==0) PS1[wid]=qs;
    grid.sync();
    float T=all_sum128(PS1,lane);
    float w=e/T;
    float incl=wave_incl_scan(w,lane);
    if(lane==63) PW1[wid]=incl;
    grid.sync();
    float off=excl_prefix128_at(PW1,lane,wid);
    C1[i]=off+incl;
    grid.sync();
    if(i==0){
      float u=jax_uniform01_scalar(key0,key1);
      int b=bsearch8192(C1,u);
      IDX[NSTEPS-1]=b;
      for(int r=NSTEPS-2;r>=0;r--){ b=(int)ANC[(size_t)r*NS+b]; IDX[r]=b; }
    }
    grid.sync();
    if(blockIdx.x==0){
      for(int e2i=tid;e2i<NSTEPS*8;e2i+=128){
        int tt=e2i>>3, d=e2i&7;
        out[e2i]=TR[((size_t)tt*NS+IDX[tt])*8+d];
      }
    }
  }
}

// ======================= launch =======================
extern "C" void kernel_launch(void* const* d_in, const int* in_sizes, int n_in,
                              void* d_out, int out_size, void* d_ws, size_t ws_size,
                              hipStream_t stream) {
  const float* obs  =(const float*)d_in[0];
  const float* inp  =(const float*)d_in[1];
  const float* mean =(const float*)d_in[2];
  const float* icov =(const float*)d_in[3];
  const float* coeff=(const float*)d_in[4];
  const float* ecov =(const float*)d_in[5];
  const float* refst=(const float*)d_in[6];
  const float* Om   =(const float*)d_in[7];
  const float* ph   =(const float*)d_in[8];
  const float* Cm   =(const float*)d_in[9];
  const int*   seedp=(const int*)d_in[10];
  float* wsf=(float*)d_ws;
  float* out=(float*)d_out;

  void* args[]={ (void*)&obs,(void*)&inp,(void*)&mean,(void*)&icov,(void*)&coeff,
                 (void*)&ecov,(void*)&refst,(void*)&Om,(void*)&ph,(void*)&Cm,
                 (void*)&seedp,(void*)&wsf,(void*)&out };
  hipLaunchCooperativeKernel((void*)k_all, dim3(64), dim3(128), args, 0, stream);
}

// Round 5
// 12798.057 us; speedup vs baseline: 1.1189x; 1.1189x over previous
//
#include <hip/hip_runtime.h>
#include <stdint.h>
#include <math.h>

#define NS 8192
#define NSTEPS 200
#define DBc 128
#define NBLK 128
#define TPB 64

typedef unsigned int u32;
typedef unsigned short u16;

// ws float-offset layout (sizes in float slots)
// NOTE round-4 bug: ANC is 199*8192 u16 = 815,104 float slots. TRACE must start
// at >= WS_ANC_F + 815104. Round 4 had TRACE at 458752 -> clobbered ANC rows
// t-1 >= 101 -> broken backward pass. Fixed here.
#define WS_BARC   0        // u32 barrier counter (own cacheline)
#define WS_BARG   32       // u32 barrier generation (own cacheline)
#define WS_KEYINIT 64      // u32[2]
#define WS_KFIN   66       // u32[2]
#define WS_KC     128      // u32[400] key chain scratch -> floats [128,528)
#define WS_KST    640      // u32[6*199] -> floats [640,1834)
#define WS_PM1    2048
#define WS_PM2    2176
#define WS_PS1    2304
#define WS_PS2    2432
#define WS_PW1    2560
#define WS_PW2    2688
#define WS_C1     4096     // 8192
#define WS_C2     12288    // 8192
#define WS_LL     20480    // 2*8192 parity -> [20480,36864)
#define WS_CF     WS_C1    // final cumsum aliases C1 (C1 dead by then)
#define WS_ANC_F  36864    // u16[199*8192] = 815104 floats -> [36864,851968)
#define WS_TRACE  851968   // float[200*8192*8] -> [851968,13959168)

// ======================= threefry2x32-20 =======================
__device__ __forceinline__ u32 rotl32(u32 v, int r){ return (v<<r)|(v>>(32-r)); }

__device__ __forceinline__ void tf2x32(u32 k0,u32 k1,u32 c0,u32 c1,u32&o0,u32&o1){
  u32 ks2 = k0^k1^0x1BD11BDAu;
  u32 x0=c0+k0, x1=c1+k1;
#define TFR(R) { x0+=x1; x1=rotl32(x1,(R)); x1^=x0; }
  TFR(13) TFR(15) TFR(26) TFR(6)
  x0+=k1;  x1+=ks2+1u;
  TFR(17) TFR(29) TFR(16) TFR(24)
  x0+=ks2; x1+=k0+2u;
  TFR(13) TFR(15) TFR(26) TFR(6)
  x0+=k0;  x1+=k1+3u;
  TFR(17) TFR(29) TFR(16) TFR(24)
  x0+=k1;  x1+=ks2+4u;
  TFR(13) TFR(15) TFR(26) TFR(6)
  x0+=ks2; x1+=k0+5u;
#undef TFR
  o0=x0; o1=x1;
}

// partitionable threefry bits (validated rounds 1-3)
__device__ __forceinline__ u32 jax_bits_elem(u32 k0,u32 k1,u32 i){
  u32 a,b; tf2x32(k0,k1,0u,i,a,b); return a^b;
}

__device__ __forceinline__ float bits_to_f01(u32 bits){
  return __uint_as_float((bits>>9)|0x3f800000u) - 1.0f;
}

__device__ __forceinline__ float log1pf_acc(float a){
#pragma clang fp contract(off)
  float u = 1.0f + a;
  if (u == 1.0f) return a;
  float l = logf(u);
  return l * (a / (u - 1.0f));
}

__device__ __forceinline__ float erfinv_xla(float x){
#pragma clang fp contract(off)
  float a = -(x*x);
  float w = -log1pf_acc(a);
  float p;
  if (w < 5.0f){
    w = w - 2.5f;
    p = 2.81022636e-08f;
    p = 3.43273939e-07f + p*w;
    p = -3.5233877e-06f + p*w;
    p = -4.39150654e-06f + p*w;
    p = 0.00021858087f  + p*w;
    p = -0.00125372503f + p*w;
    p = -0.00417768164f + p*w;
    p = 0.246640727f    + p*w;
    p = 1.50140941f     + p*w;
  } else {
    w = sqrtf(w) - 3.0f;
    p = -0.000200214257f;
    p = 0.000100950558f + p*w;
    p = 0.00134934322f  + p*w;
    p = -0.00367342844f + p*w;
    p = 0.00573950773f  + p*w;
    p = -0.0076224613f  + p*w;
    p = 0.00943887047f  + p*w;
    p = 1.00167406f     + p*w;
    p = 2.83297682f     + p*w;
  }
  return p*x;
}

__device__ __forceinline__ float jax_normal_elem(u32 k0,u32 k1,u32 i){
#pragma clang fp contract(off)
  float f = bits_to_f01(jax_bits_elem(k0,k1,i));
  float u = f*2.0f + (-0.99999994039535522f);
  u = fmaxf(-0.99999994039535522f, u);
  return 1.41421356237309515f * erfinv_xla(u);
}

__device__ __forceinline__ float jax_uniform01_scalar(u32 k0,u32 k1){
  return bits_to_f01(jax_bits_elem(k0,k1,0u));
}

// ======================= agent-scope access (cross-XCD coherent) =======================
__device__ __forceinline__ float aload(const float* p){
  return __hip_atomic_load(p, __ATOMIC_RELAXED, __HIP_MEMORY_SCOPE_AGENT);
}
__device__ __forceinline__ void astore(float* p, float v){
  __hip_atomic_store(p, v, __ATOMIC_RELAXED, __HIP_MEMORY_SCOPE_AGENT);
}

// sense-reversal grid barrier: ordering via acq/rel on gen; data coherence via
// agent-scope accesses on communicated arrays (no full L2 flush -> fast).
__device__ __forceinline__ void gridbar(u32* cnt, u32* gen, u32& g){
  __syncthreads();
  g++;
  if(threadIdx.x==0){
    u32 old=__hip_atomic_fetch_add(cnt,1u,__ATOMIC_ACQ_REL,__HIP_MEMORY_SCOPE_AGENT);
    if(old==(u32)(NBLK-1)){
      __hip_atomic_store(cnt,0u,__ATOMIC_RELAXED,__HIP_MEMORY_SCOPE_AGENT);
      __hip_atomic_store(gen,g,__ATOMIC_RELEASE,__HIP_MEMORY_SCOPE_AGENT);
    } else {
      u32 cur;
      do {
        __builtin_amdgcn_s_sleep(2);
        cur=__hip_atomic_load(gen,__ATOMIC_ACQUIRE,__HIP_MEMORY_SCOPE_AGENT);
      } while(cur<g);
    }
  }
  __syncthreads();
}

// ======================= wave helpers (bit-identical to rounds 2/3) =======================
__device__ __forceinline__ float wave_max(float v){
  #pragma unroll
  for(int m=1;m<64;m<<=1) v=fmaxf(v,__shfl_xor(v,m,64));
  return v;
}
__device__ __forceinline__ float wave_sum(float v){
  #pragma unroll
  for(int m=1;m<64;m<<=1) v+=__shfl_xor(v,m,64);
  return v;
}
__device__ __forceinline__ float wave_incl_scan(float v,int lane){
  #pragma unroll
  for(int o=1;o<64;o<<=1){ float u=__shfl_up(v,o,64); if(lane>=o) v+=u; }
  return v;
}
__device__ __forceinline__ float all_max128(const float* p,int lane){
  return wave_max(fmaxf(aload(p+lane),aload(p+lane+64)));
}
__device__ __forceinline__ float all_sum128(const float* p,int lane){
  return wave_sum(aload(p+lane)+aload(p+lane+64));
}
__device__ __forceinline__ float excl_prefix128_at(const float* p,int lane,int idx){
  float a=aload(p+lane), b=aload(p+lane+64);
  float totA=wave_sum(a);
  float sa=__shfl_up(a,1,64); if(lane==0) sa=0.0f;
  float ea=wave_incl_scan(sa,lane);
  float sb=__shfl_up(b,1,64); if(lane==0) sb=0.0f;
  float eb=wave_incl_scan(sb,lane);
  float hi=totA+eb;
  return (idx<64)? __shfl(ea,idx,64) : __shfl(hi,idx-64,64);
}

__device__ __forceinline__ int bsearch8192_a(const float* c,float v){
  int lo=0,hi=NS;
  while(lo<hi){ int mid=(lo+hi)>>1; if(aload(c+mid)<v) lo=mid+1; else hi=mid; }
  return lo>NS-1?NS-1:lo;
}
__device__ __forceinline__ int bsearch8192(const float* c,float v){
  int lo=0,hi=NS;
  while(lo<hi){ int mid=(lo+hi)>>1; if(c[mid]<v) lo=mid+1; else hi=mid; }
  return lo>NS-1?NS-1:lo;
}

__device__ void chol8(const float* A,float* L){
  for(int c=0;c<8;c++){
    for(int r=c;r<8;r++){
      float s=A[r*8+c];
      for(int k=0;k<c;k++) s-=L[r*(r+1)/2+k]*L[c*(c+1)/2+k];
      L[r*(r+1)/2+c]=(r==c)? sqrtf(s) : s/L[c*(c+1)/2+c];
    }
  }
}

// ======================= k_pre: barrier init + key chain =======================
__global__ __launch_bounds__(256) void k_pre(const int* __restrict__ seedp, float* wsf){
  u32* BARC=(u32*)(wsf+WS_BARC); u32* BARG=(u32*)(wsf+WS_BARG);
  u32* KI=(u32*)(wsf+WS_KEYINIT); u32* KF=(u32*)(wsf+WS_KFIN);
  u32* KC=(u32*)(wsf+WS_KC); u32* KST=(u32*)(wsf+WS_KST);
  int tid=threadIdx.x;
  if(tid==0){
    BARC[0]=0u; BARG[0]=0u;
    u32 s=(u32)seedp[0];
    u32 a,b;
    tf2x32(0u,s,0u,0u,a,b); KC[0]=a; KC[1]=b;      // key_0 = split(key).child0
    tf2x32(0u,s,0u,1u,a,b); KI[0]=a; KI[1]=b;      // key_init = child1
    for(int t=1;t<NSTEPS;t++){
      tf2x32(KC[2*(t-1)],KC[2*(t-1)+1],0u,0u,a,b); // key_t = split(key_{t-1}).child0
      KC[2*t]=a; KC[2*t+1]=b;
    }
    KF[0]=KC[2*(NSTEPS-1)]; KF[1]=KC[2*(NSTEPS-1)+1];
  }
  __syncthreads();
  int t=tid;
  if(t>=1 && t<NSTEPS){
    u32 k0=KC[2*(t-1)], k1=KC[2*(t-1)+1];
    u32 s0,s1; tf2x32(k0,k1,0u,1u,s0,s1);          // key_step = child1
    u32 ka0,ka1; tf2x32(s0,s1,0u,1u,ka0,ka1);      // k_anc
    u32 t0,t1;  tf2x32(s0,s1,0u,0u,t0,t1);         // key_step'
    u32 kr0,kr1; tf2x32(t0,t1,0u,1u,kr0,kr1);      // k_ref
    u32 u0,u1;  tf2x32(t0,t1,0u,0u,u0,u1);         // key_step''
    u32 w0,w1;  tf2x32(u0,u1,0u,1u,w0,w1);         // k_state
    u32* p=KST+6*(t-1);
    p[0]=ka0;p[1]=ka1;p[2]=kr0;p[3]=kr1;p[4]=w0;p[5]=w1;
  }
}

// ======================= k_all: fused scan (own barrier) =======================
__global__ __launch_bounds__(TPB) void k_all(
    const float* __restrict__ obs, const float* __restrict__ inp,
    const float* __restrict__ mean, const float* __restrict__ icov,
    const float* __restrict__ coeff, const float* __restrict__ ecov,
    const float* __restrict__ refst, const float* __restrict__ Om,
    const float* __restrict__ ph, const float* __restrict__ Cm,
    float* wsf)
{
  const int lane=threadIdx.x;
  const int wid=blockIdx.x;
  const int i=blockIdx.x*TPB+lane;

  u32* BARC=(u32*)(wsf+WS_BARC); u32* BARG=(u32*)(wsf+WS_BARG);
  const u32* KI=(const u32*)(wsf+WS_KEYINIT);
  const u32* KST=(const u32*)(wsf+WS_KST);
  float* C1=wsf+WS_C1;  float* C2=wsf+WS_C2;
  float* PM1=wsf+WS_PM1; float* PM2=wsf+WS_PM2;
  float* PS1=wsf+WS_PS1; float* PS2=wsf+WS_PS2;
  float* PW1=wsf+WS_PW1; float* PW2=wsf+WS_PW2;
  float* LLb=wsf+WS_LL;
  float* CF=wsf+WS_CF;
  u16* ANC=(u16*)(wsf+WS_ANC_F);
  float* TR=wsf+WS_TRACE;
  u32 g=0;

  float LEp[36];
  { float L0p[36];
    chol8(icov,L0p); chol8(ecov,LEp);
    float st[8];
    if(i==NS-1){ for(int d=0;d<8;d++) st[d]=refst[d]; }
    else {
      float eps[8];
      for(int d=0;d<8;d++) eps[d]=jax_normal_elem(KI[0],KI[1],(u32)(i*8+d));
      for(int d=0;d<8;d++){ float m=0.0f; for(int k=0;k<=d;k++) m+=eps[k]*L0p[d*(d+1)/2+k]; st[d]=mean[d]+m; }
    }
    for(int d=0;d<8;d++) TR[i*8+d]=st[d];

    float c_ll=4.0f*logf((float)(2.0*M_PI*0.1*0.1));
    float hc1=0.0f; for(int d=0;d<8;d++) hc1+=logf(LEp[d*(d+1)/2+d]);
    float hc2=4.0f*logf((float)(2.0*M_PI));
    const float SSQ=(float)(0.1*0.1);
    float lw=0.0f;

    for(int t=1;t<NSTEPS;t++){
      const u32* kp=KST+6*(t-1);
      u32 ka0=kp[0],ka1=kp[1],kr0=kp[2],kr1=kp[3],kst0=kp[4],kst1=kp[5];

      // --- phase A (state-exact arithmetic, identical to rounds 2/3) ---
      float z[12];
      for(int d=0;d<8;d++) z[d]=st[d];
      for(int k=0;k<4;k++) z[8+k]=inp[t*4+k];
      float ax[8]={0,0,0,0,0,0,0,0};
      for(int j=0;j<DBc;j++){
        float dot=0.0f;
        #pragma unroll
        for(int k=0;k<12;k++) dot+=z[k]*Om[j*12+k];
        float b=cosf(dot+ph[j]);
        #pragma unroll
        for(int d=0;d<8;d++) ax[d]+=b*coeff[d*DBc+j];
      }
      float S=0.0f;
      for(int d=0;d<8;d++){
        float m=0.0f;
        #pragma unroll
        for(int k=0;k<8;k++) m+=ax[k]*Cm[d*8+k];
        float r=obs[t*8+d]-m; S+=r*r;
      }
      float ll=(-0.5f*S)/SSQ - c_ll;
      float sol[8]; float q=0.0f;
      for(int d=0;d<8;d++){
        float s=refst[t*8+d]-ax[d];
        for(int k=0;k<d;k++) s-=LEp[d*(d+1)/2+k]*sol[k];
        sol[d]=s/LEp[d*(d+1)/2+d];
        q+=sol[d]*sol[d];
      }
      float h=(-0.5f*q - hc1) - hc2;
      float s1v=ll+lw, s2v=s1v+h;
      astore(LLb+(t&1)*NS+i, ll);
      float wm1=wave_max(s1v), wm2=wave_max(s2v);
      if(lane==0){ astore(PM1+wid,wm1); astore(PM2+wid,wm2); }
      gridbar(BARC,BARG,g);

      // --- B1: global max, exp, wave sums ---
      float M1=all_max128(PM1,lane), M2=all_max128(PM2,lane);
      float e1=expf(s1v-M1), e2=expf(s2v-M2);
      float q1=wave_sum(e1), q2=wave_sum(e2);
      if(lane==0){ astore(PS1+wid,q1); astore(PS2+wid,q2); }
      gridbar(BARC,BARG,g);

      // --- B2: totals, normalize, wave scans ---
      float T1=all_sum128(PS1,lane), T2=all_sum128(PS2,lane);
      float w1=e1/T1, w2=e2/T2;
      float in1=wave_incl_scan(w1,lane), in2=wave_incl_scan(w2,lane);
      if(lane==63){ astore(PW1+wid,in1); astore(PW2+wid,in2); }
      gridbar(BARC,BARG,g);

      // --- B3: global cumsum ---
      float off1=excl_prefix128_at(PW1,lane,wid);
      float off2=excl_prefix128_at(PW2,lane,wid);
      astore(C1+i, off1+in1);
      astore(C2+i, off2+in2);
      gridbar(BARC,BARG,g);

      // --- D: resample, propagate, reweight, trace ---
      int aidx;
      if(i==NS-1){
        float u2=jax_uniform01_scalar(kr0,kr1);
        aidx=bsearch8192_a(C2,u2);
      } else {
        float u1=jax_uniform01_scalar(ka0,ka1);
        float pos=((float)i+u1)*(1.0f/8192.0f);
        aidx=bsearch8192_a(C1,pos);
      }
      ANC[(size_t)(t-1)*NS+i]=(u16)aidx;

      if(i==NS-1){ for(int d=0;d<8;d++) st[d]=refst[t*8+d]; }
      else {
        float eps[8];
        for(int d=0;d<8;d++) eps[d]=jax_normal_elem(kst0,kst1,(u32)(i*8+d));
        for(int d=0;d<8;d++){ float m=0.0f; for(int k=0;k<=d;k++) m+=eps[k]*LEp[d*(d+1)/2+k]; st[d]=ax[d]+m; }
      }
      float S2n=0.0f;
      for(int d=0;d<8;d++){
        float m=0.0f;
        #pragma unroll
        for(int k=0;k<8;k++) m+=st[k]*Cm[d*8+k];
        float r=obs[t*8+d]-m; S2n+=r*r;
      }
      float lln=(-0.5f*S2n)/SSQ - c_ll;
      lw=lln-aload(LLb+(t&1)*NS+aidx);
      float* TRt=TR+(size_t)t*NS*8;
      for(int d=0;d<8;d++) TRt[i*8+d]=st[d];
      // no barrier: LL parity-buffered; C1/C2/PM/PS rewritten >=2 barriers later
    }

    // ===== final weights -> cumsum (read by k_post) =====
    float wm=wave_max(lw);
    if(lane==0) astore(PM1+wid,wm);
    gridbar(BARC,BARG,g);
    float M=all_max128(PM1,lane);
    float e=expf(lw-M);
    float qs=wave_sum(e);
    if(lane==0) astore(PS1+wid,qs);
    gridbar(BARC,BARG,g);
    float T=all_sum128(PS1,lane);
    float w=e/T;
    float incl=wave_incl_scan(w,lane);
    if(lane==63) astore(PW1+wid,incl);
    gridbar(BARC,BARG,g);
    float off=excl_prefix128_at(PW1,lane,wid);
    CF[i]=off+incl;    // plain: consumed by next dispatch (CF aliases C1; C1 dead)
  }
}

// ======================= k_post: final draw + backward + gather =======================
__global__ __launch_bounds__(256) void k_post(const float* __restrict__ wsf, float* __restrict__ out){
  __shared__ int IDXs[NSTEPS];
  const u32* KF=(const u32*)(wsf+WS_KFIN);
  const float* CF=wsf+WS_CF;
  const u16* ANC=(const u16*)(wsf+WS_ANC_F);
  const float* TR=wsf+WS_TRACE;
  if(threadIdx.x==0){
    float u=jax_uniform01_scalar(KF[0],KF[1]);
    int b=bsearch8192(CF,u);
    IDXs[NSTEPS-1]=b;
    for(int r=NSTEPS-2;r>=0;r--){ b=(int)ANC[(size_t)r*NS+b]; IDXs[r]=b; }
  }
  __syncthreads();
  for(int e=threadIdx.x;e<NSTEPS*8;e+=256){
    int t=e>>3,d=e&7;
    out[e]=TR[((size_t)t*NS+IDXs[t])*8+d];
  }
}

// ======================= launch =======================
extern "C" void kernel_launch(void* const* d_in, const int* in_sizes, int n_in,
                              void* d_out, int out_size, void* d_ws, size_t ws_size,
                              hipStream_t stream) {
  const float* obs  =(const float*)d_in[0];
  const float* inp  =(const float*)d_in[1];
  const float* mean =(const float*)d_in[2];
  const float* icov =(const float*)d_in[3];
  const float* coeff=(const float*)d_in[4];
  const float* ecov =(const float*)d_in[5];
  const float* refst=(const float*)d_in[6];
  const float* Om   =(const float*)d_in[7];
  const float* ph   =(const float*)d_in[8];
  const float* Cm   =(const float*)d_in[9];
  const int*   seedp=(const int*)d_in[10];
  float* wsf=(float*)d_ws;
  float* out=(float*)d_out;

  hipLaunchKernelGGL(k_pre, dim3(1), dim3(256), 0, stream, seedp, wsf);

  void* args[]={ (void*)&obs,(void*)&inp,(void*)&mean,(void*)&icov,(void*)&coeff,
                 (void*)&ecov,(void*)&refst,(void*)&Om,(void*)&ph,(void*)&Cm,
                 (void*)&wsf };
  hipLaunchCooperativeKernel((void*)k_all, dim3(NBLK), dim3(TPB), args, 0, stream);

  hipLaunchKernelGGL(k_post, dim3(1), dim3(256), 0, stream, wsf, out);
}

// Round 6
// 11049.918 us; speedup vs baseline: 1.2959x; 1.1582x over previous
//
#include <hip/hip_runtime.h>
#include <stdint.h>
#include <math.h>

#define NS 8192
#define NSTEPS 200
#define DBc 128
#define NBLK 32
#define TPB 256

typedef unsigned int u32;
typedef unsigned short u16;

// ws float-offset layout (float slots)
#define WS_BARC   0        // u32 barrier counter
#define WS_BARG   32       // u32 barrier generation
#define WS_KEYINIT 64      // u32[2]
#define WS_KFIN   66       // u32[2]
#define WS_KC     128      // u32[400]
#define WS_KST    640      // u32[6*199]
#define WS_PM1    2048     // [2][128] per-wave max (S1)
#define WS_PE1    2304     // [2][128] per-wave sumexp (S1)
#define WS_PM2    2560     // [2][128] (S2)
#define WS_PE2    2816     // [2][128] (S2)
#define WS_S1     4096     // [2][8192] scores s1
#define WS_S2     20480    // [2][8192] scores s2
#define WS_LL     36864    // [2][8192] ll_aux
#define WS_LWF    WS_S2    // final log-weights alias S2 parity0 (dead at that point)
#define WS_ANC_F  53248    // u16[199*8192] = 815104 floats -> [53248,868352)
#define WS_TRACE  868352   // float[200*8192*8] -> ends 13,975,552

// ======================= threefry2x32-20 =======================
__device__ __forceinline__ u32 rotl32(u32 v, int r){ return (v<<r)|(v>>(32-r)); }

__device__ __forceinline__ void tf2x32(u32 k0,u32 k1,u32 c0,u32 c1,u32&o0,u32&o1){
  u32 ks2 = k0^k1^0x1BD11BDAu;
  u32 x0=c0+k0, x1=c1+k1;
#define TFR(R) { x0+=x1; x1=rotl32(x1,(R)); x1^=x0; }
  TFR(13) TFR(15) TFR(26) TFR(6)
  x0+=k1;  x1+=ks2+1u;
  TFR(17) TFR(29) TFR(16) TFR(24)
  x0+=ks2; x1+=k0+2u;
  TFR(13) TFR(15) TFR(26) TFR(6)
  x0+=k0;  x1+=k1+3u;
  TFR(17) TFR(29) TFR(16) TFR(24)
  x0+=k1;  x1+=ks2+4u;
  TFR(13) TFR(15) TFR(26) TFR(6)
  x0+=ks2; x1+=k0+5u;
#undef TFR
  o0=x0; o1=x1;
}

__device__ __forceinline__ u32 jax_bits_elem(u32 k0,u32 k1,u32 i){
  u32 a,b; tf2x32(k0,k1,0u,i,a,b); return a^b;
}

__device__ __forceinline__ float bits_to_f01(u32 bits){
  return __uint_as_float((bits>>9)|0x3f800000u) - 1.0f;
}

__device__ __forceinline__ float log1pf_acc(float a){
#pragma clang fp contract(off)
  float u = 1.0f + a;
  if (u == 1.0f) return a;
  float l = logf(u);
  return l * (a / (u - 1.0f));
}

__device__ __forceinline__ float erfinv_xla(float x){
#pragma clang fp contract(off)
  float a = -(x*x);
  float w = -log1pf_acc(a);
  float p;
  if (w < 5.0f){
    w = w - 2.5f;
    p = 2.81022636e-08f;
    p = 3.43273939e-07f + p*w;
    p = -3.5233877e-06f + p*w;
    p = -4.39150654e-06f + p*w;
    p = 0.00021858087f  + p*w;
    p = -0.00125372503f + p*w;
    p = -0.00417768164f + p*w;
    p = 0.246640727f    + p*w;
    p = 1.50140941f     + p*w;
  } else {
    w = sqrtf(w) - 3.0f;
    p = -0.000200214257f;
    p = 0.000100950558f + p*w;
    p = 0.00134934322f  + p*w;
    p = -0.00367342844f + p*w;
    p = 0.00573950773f  + p*w;
    p = -0.0076224613f  + p*w;
    p = 0.00943887047f  + p*w;
    p = 1.00167406f     + p*w;
    p = 2.83297682f     + p*w;
  }
  return p*x;
}

__device__ __forceinline__ float jax_normal_elem(u32 k0,u32 k1,u32 i){
#pragma clang fp contract(off)
  float f = bits_to_f01(jax_bits_elem(k0,k1,i));
  float u = f*2.0f + (-0.99999994039535522f);
  u = fmaxf(-0.99999994039535522f, u);
  return 1.41421356237309515f * erfinv_xla(u);
}

__device__ __forceinline__ float jax_uniform01_scalar(u32 k0,u32 k1){
  return bits_to_f01(jax_bits_elem(k0,k1,0u));
}

// ======================= agent-scope access (cross-XCD coherent) =======================
__device__ __forceinline__ float aload(const float* p){
  return __hip_atomic_load(p, __ATOMIC_RELAXED, __HIP_MEMORY_SCOPE_AGENT);
}
__device__ __forceinline__ void astore(float* p, float v){
  __hip_atomic_store(p, v, __ATOMIC_RELAXED, __HIP_MEMORY_SCOPE_AGENT);
}

// sense-reversal grid barrier (validated round 5); relaxed poll + final acquire
__device__ __forceinline__ void gridbar(u32* cnt, u32* gen, u32& g){
  __syncthreads();
  g++;
  if(threadIdx.x==0){
    u32 old=__hip_atomic_fetch_add(cnt,1u,__ATOMIC_ACQ_REL,__HIP_MEMORY_SCOPE_AGENT);
    if(old==(u32)(NBLK-1)){
      __hip_atomic_store(cnt,0u,__ATOMIC_RELAXED,__HIP_MEMORY_SCOPE_AGENT);
      __hip_atomic_store(gen,g,__ATOMIC_RELEASE,__HIP_MEMORY_SCOPE_AGENT);
    } else {
      u32 cur;
      do {
        __builtin_amdgcn_s_sleep(4);
        cur=__hip_atomic_load(gen,__ATOMIC_RELAXED,__HIP_MEMORY_SCOPE_AGENT);
      } while(cur<g);
      (void)__hip_atomic_load(gen,__ATOMIC_ACQUIRE,__HIP_MEMORY_SCOPE_AGENT);
    }
  }
  __syncthreads();
}

// ======================= wave helpers =======================
__device__ __forceinline__ float wave_max(float v){
  #pragma unroll
  for(int m=1;m<64;m<<=1) v=fmaxf(v,__shfl_xor(v,m,64));
  return v;
}
__device__ __forceinline__ float wave_sum(float v){
  #pragma unroll
  for(int m=1;m<64;m<<=1) v+=__shfl_xor(v,m,64);
  return v;
}
__device__ __forceinline__ float wave_incl_scan(float v,int lane){
  #pragma unroll
  for(int o=1;o<64;o<<=1){ float u=__shfl_up(v,o,64); if(lane>=o) v+=u; }
  return v;
}

__device__ __forceinline__ int bsearch8192(const float* c,float v){
  int lo=0,hi=NS;
  while(lo<hi){ int mid=(lo+hi)>>1; if(c[mid]<v) lo=mid+1; else hi=mid; }
  return lo>NS-1?NS-1:lo;
}

__device__ void chol8(const float* A,float* L){
  for(int c=0;c<8;c++){
    for(int r=c;r<8;r++){
      float s=A[r*8+c];
      for(int k=0;k<c;k++) s-=L[r*(r+1)/2+k]*L[c*(c+1)/2+k];
      L[r*(r+1)/2+c]=(r==c)? sqrtf(s) : s/L[c*(c+1)/2+c];
    }
  }
}

// ======================= k_pre: barrier init + key chain =======================
__global__ __launch_bounds__(256) void k_pre(const int* __restrict__ seedp, float* wsf){
  u32* BARC=(u32*)(wsf+WS_BARC); u32* BARG=(u32*)(wsf+WS_BARG);
  u32* KI=(u32*)(wsf+WS_KEYINIT); u32* KF=(u32*)(wsf+WS_KFIN);
  u32* KC=(u32*)(wsf+WS_KC); u32* KST=(u32*)(wsf+WS_KST);
  int tid=threadIdx.x;
  if(tid==0){
    BARC[0]=0u; BARG[0]=0u;
    u32 s=(u32)seedp[0];
    u32 a,b;
    tf2x32(0u,s,0u,0u,a,b); KC[0]=a; KC[1]=b;      // key_0 = split(key).child0
    tf2x32(0u,s,0u,1u,a,b); KI[0]=a; KI[1]=b;      // key_init = child1
    for(int t=1;t<NSTEPS;t++){
      tf2x32(KC[2*(t-1)],KC[2*(t-1)+1],0u,0u,a,b);
      KC[2*t]=a; KC[2*t+1]=b;
    }
    KF[0]=KC[2*(NSTEPS-1)]; KF[1]=KC[2*(NSTEPS-1)+1];
  }
  __syncthreads();
  int t=tid;
  if(t>=1 && t<NSTEPS){
    u32 k0=KC[2*(t-1)], k1=KC[2*(t-1)+1];
    u32 s0,s1; tf2x32(k0,k1,0u,1u,s0,s1);          // key_step
    u32 ka0,ka1; tf2x32(s0,s1,0u,1u,ka0,ka1);      // k_anc
    u32 t0,t1;  tf2x32(s0,s1,0u,0u,t0,t1);
    u32 kr0,kr1; tf2x32(t0,t1,0u,1u,kr0,kr1);      // k_ref
    u32 u0,u1;  tf2x32(t0,t1,0u,0u,u0,u1);
    u32 w0,w1;  tf2x32(u0,u1,0u,1u,w0,w1);         // k_state
    u32* p=KST+6*(t-1);
    p[0]=ka0;p[1]=ka1;p[2]=kr0;p[3]=kr1;p[4]=w0;p[5]=w1;
  }
}

// ======================= k_all: fused scan, ONE grid barrier per step =======================
__global__ __launch_bounds__(TPB) void k_all(
    const float* __restrict__ obs, const float* __restrict__ inp,
    const float* __restrict__ mean, const float* __restrict__ icov,
    const float* __restrict__ coeff, const float* __restrict__ ecov,
    const float* __restrict__ refst, const float* __restrict__ Om,
    const float* __restrict__ ph, const float* __restrict__ Cm,
    float* wsf)
{
  const int tid=threadIdx.x;
  const int lane=tid&63;
  const int wib=tid>>6;                 // wave in block 0..3
  const int i=blockIdx.x*TPB+tid;       // particle id
  const int gw=i>>6;                    // global wave 0..127

  u32* BARC=(u32*)(wsf+WS_BARC); u32* BARG=(u32*)(wsf+WS_BARG);
  const u32* KI=(const u32*)(wsf+WS_KEYINIT);
  const u32* KST=(const u32*)(wsf+WS_KST);
  float* S1=wsf+WS_S1; float* S2=wsf+WS_S2;
  float* PM1=wsf+WS_PM1; float* PE1=wsf+WS_PE1;
  float* PM2=wsf+WS_PM2; float* PE2=wsf+WS_PE2;
  float* LLb=wsf+WS_LL;
  float* LWF=wsf+WS_LWF;
  u16* ANC=(u16*)(wsf+WS_ANC_F);
  float* TR=wsf+WS_TRACE;
  u32 g=0;

  __shared__ float EX1[128];   // raw exclusive prefix per wave (S1)
  __shared__ float EX2[128];   // (S2)
  __shared__ float MT[4];      // M1,T1,M2,T2 (T raw scale)

  float LEp[36];
  { float L0p[36];
    chol8(icov,L0p); chol8(ecov,LEp);
    float st[8];
    if(i==NS-1){ for(int d=0;d<8;d++) st[d]=refst[d]; }
    else {
      float eps[8];
      for(int d=0;d<8;d++) eps[d]=jax_normal_elem(KI[0],KI[1],(u32)(i*8+d));
      for(int d=0;d<8;d++){ float m=0.0f; for(int k=0;k<=d;k++) m+=eps[k]*L0p[d*(d+1)/2+k]; st[d]=mean[d]+m; }
    }
    for(int d=0;d<8;d++) TR[i*8+d]=st[d];

    float c_ll=4.0f*logf((float)(2.0*M_PI*0.1*0.1));
    float hc1=0.0f; for(int d=0;d<8;d++) hc1+=logf(LEp[d*(d+1)/2+d]);
    float hc2=4.0f*logf((float)(2.0*M_PI));
    const float SSQ=(float)(0.1*0.1);
    float lw=0.0f;

    for(int t=1;t<NSTEPS;t++){
      const u32* kp=KST+6*(t-1);
      u32 ka0=kp[0],ka1=kp[1],kr0=kp[2],kr1=kp[3],kst0=kp[4],kst1=kp[5];
      const int par=t&1;
      float* S1p=S1+par*NS; float* S2p=S2+par*NS; float* LLp=LLb+par*NS;
      float* PM1p=PM1+par*128; float* PE1p=PE1+par*128;
      float* PM2p=PM2+par*128; float* PE2p=PE2+par*128;

      // --- A: state-exact arithmetic (byte-identical to rounds 2-5) ---
      float z[12];
      for(int d=0;d<8;d++) z[d]=st[d];
      for(int k=0;k<4;k++) z[8+k]=inp[t*4+k];
      float ax[8]={0,0,0,0,0,0,0,0};
      for(int j=0;j<DBc;j++){
        float dot=0.0f;
        #pragma unroll
        for(int k=0;k<12;k++) dot+=z[k]*Om[j*12+k];
        float b=cosf(dot+ph[j]);
        #pragma unroll
        for(int d=0;d<8;d++) ax[d]+=b*coeff[d*DBc+j];
      }
      float S=0.0f;
      for(int d=0;d<8;d++){
        float m=0.0f;
        #pragma unroll
        for(int k=0;k<8;k++) m+=ax[k]*Cm[d*8+k];
        float r=obs[t*8+d]-m; S+=r*r;
      }
      float ll=(-0.5f*S)/SSQ - c_ll;
      float sol[8]; float q=0.0f;
      for(int d=0;d<8;d++){
        float s=refst[t*8+d]-ax[d];
        for(int k=0;k<d;k++) s-=LEp[d*(d+1)/2+k]*sol[k];
        sol[d]=s/LEp[d*(d+1)/2+d];
        q+=sol[d]*sol[d];
      }
      float h=(-0.5f*q - hc1) - hc2;
      float s1v=ll+lw, s2v=s1v+h;
      astore(S1p+i,s1v); astore(S2p+i,s2v); astore(LLp+i,ll);
      float m1=wave_max(s1v); float se1=wave_sum(expf(s1v-m1));
      float m2=wave_max(s2v); float se2=wave_sum(expf(s2v-m2));
      if(lane==0){ astore(PM1p+gw,m1); astore(PE1p+gw,se1);
                   astore(PM2p+gw,m2); astore(PE2p+gw,se2); }
      gridbar(BARC,BARG,g);   // the ONE barrier per step

      // --- B: block-redundant online-softmax combine (waves 0,1) ---
      if(wib<2){
        const float* PMp=(wib==0)?PM1p:PM2p;
        const float* PEp=(wib==0)?PE1p:PE2p;
        float* EX=(wib==0)?EX1:EX2;
        float a=aload(PMp+lane), b=aload(PMp+64+lane);
        float M=wave_max(fmaxf(a,b));
        float ga=aload(PEp+lane)*expf(a-M);
        float gb=aload(PEp+64+lane)*expf(b-M);
        float sA=wave_incl_scan(ga,lane);
        float totA=__shfl(sA,63,64);
        float sB=wave_incl_scan(gb,lane);
        float totB=__shfl(sB,63,64);
        EX[lane]=sA-ga;
        EX[64+lane]=totA+(sB-gb);
        if(lane==0){ MT[wib*2]=M; MT[wib*2+1]=totA+totB; }
      }
      __syncthreads();

      // --- D: resample via (LDS wave-search + foreign-wave scan), propagate ---
      bool isref=(i==NS-1);
      float tau,Mx; const float* Sb; const float* EX;
      if(isref){
        float u2=jax_uniform01_scalar(kr0,kr1);
        tau=u2*MT[3]; Mx=MT[2]; Sb=S2p; EX=EX2;
      } else {
        float u1=jax_uniform01_scalar(ka0,ka1);
        float pos=((float)i+u1)*(1.0f/8192.0f);
        tau=pos*MT[1]; Mx=MT[0]; Sb=S1p; EX=EX1;
      }
      int lo=0,hi=127;
      while(lo<hi){ int mid=(lo+hi+1)>>1; if(EX[mid]<=tau) lo=mid; else hi=mid-1; }
      int wt=lo;
      float c=EX[wt];
      int fj=-1;
      for(int j=0;j<64;j++){
        float sv=aload(Sb+(wt<<6)+j);
        c+=expf(sv-Mx);
        if(fj<0 && c>=tau) fj=j;
      }
      int aidx;
      if(fj>=0) aidx=(wt<<6)+fj;
      else { int nx=(wt<<6)+64; aidx=(nx>NS-1)?NS-1:nx; }
      ANC[(size_t)(t-1)*NS+i]=(u16)aidx;

      if(isref){ for(int d=0;d<8;d++) st[d]=refst[t*8+d]; }
      else {
        float eps[8];
        for(int d=0;d<8;d++) eps[d]=jax_normal_elem(kst0,kst1,(u32)(i*8+d));
        for(int d=0;d<8;d++){ float m=0.0f; for(int k=0;k<=d;k++) m+=eps[k]*LEp[d*(d+1)/2+k]; st[d]=ax[d]+m; }
      }
      float S2n=0.0f;
      for(int d=0;d<8;d++){
        float m=0.0f;
        #pragma unroll
        for(int k=0;k<8;k++) m+=st[k]*Cm[d*8+k];
        float r=obs[t*8+d]-m; S2n+=r*r;
      }
      float lln=(-0.5f*S2n)/SSQ - c_ll;
      lw=lln-aload(LLp+aidx);
      float* TRt=TR+(size_t)t*NS*8;
      for(int d=0;d<8;d++) TRt[i*8+d]=st[d];
      // no barrier D->A: next A writes parity-swapped buffers; EX overwrite
      // separated by gridbar's internal __syncthreads.
    }
    LWF[i]=lw;   // plain store; consumed by k_post (dispatch boundary)
  }
}

// ======================= k_post: final softmax + draw + backward + gather =======================
__global__ __launch_bounds__(1024) void k_post(const float* __restrict__ wsf, float* __restrict__ out){
  __shared__ float sh[NS];
  __shared__ float r1[1024];
  __shared__ float r2[1024];
  __shared__ int IDXs[NSTEPS];
  int tid=threadIdx.x; int base=tid*8;
  const float* LW=wsf+WS_LWF;
  const u32* KF=(const u32*)(wsf+WS_KFIN);
  const u16* ANC=(const u16*)(wsf+WS_ANC_F);
  const float* TR=wsf+WS_TRACE;
  float v[8]; float m=-INFINITY;
  for(int k=0;k<8;k++){ v[k]=LW[base+k]; m=fmaxf(m,v[k]); }
  r1[tid]=m; __syncthreads();
  for(int off=512;off>0;off>>=1){ if(tid<off) r1[tid]=fmaxf(r1[tid],r1[tid+off]); __syncthreads(); }
  float M=r1[0]; __syncthreads();
  float e[8]; float cs=0.0f;
  for(int k=0;k<8;k++){ e[k]=expf(v[k]-M); cs+=e[k]; }
  r1[tid]=cs; __syncthreads();
  for(int off=512;off>0;off>>=1){ if(tid<off) r1[tid]+=r1[tid+off]; __syncthreads(); }
  float T=r1[0]; __syncthreads();
  float w[8]; float wcs=0.0f;
  for(int k=0;k<8;k++){ w[k]=e[k]/T; wcs+=w[k]; }
  float* src=r1; float* dst=r2;
  src[tid]=wcs; __syncthreads();
  for(int off=1;off<1024;off<<=1){
    float x=src[tid]; if(tid>=off) x+=src[tid-off];
    dst[tid]=x; __syncthreads(); float* tmp=src; src=dst; dst=tmp;
  }
  float excl=(tid==0)?0.0f:src[tid-1];
  __syncthreads();
  float run=excl;
  for(int k=0;k<8;k++){ run+=w[k]; sh[base+k]=run; }
  __syncthreads();
  if(tid==0){
    float u=jax_uniform01_scalar(KF[0],KF[1]);
    int b=bsearch8192(sh,u);
    IDXs[NSTEPS-1]=b;
    for(int r=NSTEPS-2;r>=0;r--){ b=(int)ANC[(size_t)r*NS+b]; IDXs[r]=b; }
  }
  __syncthreads();
  for(int e2=tid;e2<NSTEPS*8;e2+=1024){
    int t=e2>>3,d=e2&7;
    out[e2]=TR[((size_t)t*NS+IDXs[t])*8+d];
  }
}

// ======================= launch =======================
extern "C" void kernel_launch(void* const* d_in, const int* in_sizes, int n_in,
                              void* d_out, int out_size, void* d_ws, size_t ws_size,
                              hipStream_t stream) {
  const float* obs  =(const float*)d_in[0];
  const float* inp  =(const float*)d_in[1];
  const float* mean =(const float*)d_in[2];
  const float* icov =(const float*)d_in[3];
  const float* coeff=(const float*)d_in[4];
  const float* ecov =(const float*)d_in[5];
  const float* refst=(const float*)d_in[6];
  const float* Om   =(const float*)d_in[7];
  const float* ph   =(const float*)d_in[8];
  const float* Cm   =(const float*)d_in[9];
  const int*   seedp=(const int*)d_in[10];
  float* wsf=(float*)d_ws;
  float* out=(float*)d_out;

  hipLaunchKernelGGL(k_pre, dim3(1), dim3(256), 0, stream, seedp, wsf);

  void* args[]={ (void*)&obs,(void*)&inp,(void*)&mean,(void*)&icov,(void*)&coeff,
                 (void*)&ecov,(void*)&refst,(void*)&Om,(void*)&ph,(void*)&Cm,
                 (void*)&wsf };
  hipLaunchCooperativeKernel((void*)k_all, dim3(NBLK), dim3(TPB), args, 0, stream);

  hipLaunchKernelGGL(k_post, dim3(1), dim3(1024), 0, stream, wsf, out);
}